// Round 6
// baseline (291.715 us; speedup 1.0000x reference)
//
#include <hip/hip_runtime.h>
#include <cfloat>

// Problem constants
#define BS 16
#define CC 512
#define HWD 1024      // h*w
#define NN 16384      // BS*HWD rows
#define MM 8          // sub-codebooks
#define NE 1024       // codes per sub-codebook
#define ED 64         // code dim

// d_out layout (all read back as float32):
#define LOSS_OFF 8388608
#define IDX_OFF  8388609
#define BIN_OFF  8519681

// flag margin: ref fp32 quantization perturbs d by <=~1.5e-5; phase-1 err ~3e-6
#define TAU 4e-5f
// candidate window in raw float-bit units (>= 2.38e-5 in value space)
#define UWIN 400u

// workspace byte offsets
#define WS_B     0            // float[MM*NE] emulated np ||e||^2
#define WS_IDX   32768        // int[MM*NN]
#define WS_CNT   557056       // int[2]: flag count, overflow count (+pad 32)
#define WS_LIST  557088       // int[32768] flagged rows
#define WS_OF    688160       // int[8192] overflow rows
#define WS_CANDK 720928       // int[32768*12] candidate code ids
#define WS_CANDU 2293792      // uint[32768*12] candidate masked dists
#define WS_BMAT  3866656      // uint4[8*13*32*64] bf16 frag-order B (3.25 MB)

typedef __attribute__((ext_vector_type(8))) short bf16x8;
typedef __attribute__((ext_vector_type(16))) float f32x16;

// ---- bf16 helpers ---------------------------------------------------------
__device__ __forceinline__ unsigned short f2bf(float f) {
    unsigned int u = __float_as_uint(f);
    unsigned int r = (u + 0x7fffu + ((u >> 16) & 1u)) >> 16;
    return (unsigned short)r;
}
__device__ __forceinline__ float bf2f(unsigned short h) {
    return __uint_as_float(((unsigned int)h) << 16);
}
__device__ __forceinline__ unsigned umin_(unsigned a, unsigned b) { return a < b ? a : b; }
__device__ __forceinline__ unsigned umax_(unsigned a, unsigned b) { return a > b ? a : b; }
__device__ __forceinline__ unsigned umin3(unsigned a, unsigned b, unsigned c) {
    return umin_(umin_(a, b), c);
}

// ---- fp32 ops with contraction disabled -----------------------------------
__device__ __forceinline__ float mul_rn(float a, float b) {
#pragma clang fp contract(off)
    return a * b;
}
__device__ __forceinline__ float add_rn(float a, float b) {
#pragma clang fp contract(off)
    return a + b;
}
__device__ __forceinline__ float sub_rn(float a, float b) {
#pragma clang fp contract(off)
    return a - b;
}

// numpy FLOAT_pairwise_sum over fl(x_d^2), n=64
__device__ __forceinline__ float np_sumsq64(const float* x) {
    float r[8];
#pragma unroll
    for (int j = 0; j < 8; ++j) r[j] = mul_rn(x[j], x[j]);
#pragma unroll
    for (int i = 8; i < 64; i += 8) {
#pragma unroll
        for (int j = 0; j < 8; ++j) r[j] = add_rn(r[j], mul_rn(x[i + j], x[i + j]));
    }
    return add_rn(add_rn(add_rn(r[0], r[1]), add_rn(r[2], r[3])),
                  add_rn(add_rn(r[4], r[5]), add_rn(r[6], r[7])));
}

// numpy einsum sum_of_products_contig_two, SSE npyv (no FMA); z from LDS ptr
__device__ __forceinline__ float np_dot64(const float* zsh, const float4* cr4) {
    float v0 = 0.f, v1 = 0.f, v2 = 0.f, v3 = 0.f;
#pragma unroll
    for (int t = 0; t < 4; ++t) {
        float4 e0 = cr4[t * 4 + 0];
        float4 e1 = cr4[t * 4 + 1];
        float4 e2 = cr4[t * 4 + 2];
        float4 e3 = cr4[t * 4 + 3];
        const int d0 = 16 * t;
        v0 = add_rn(mul_rn(zsh[d0 + 0], e0.x),
             add_rn(mul_rn(zsh[d0 + 4], e1.x),
             add_rn(mul_rn(zsh[d0 + 8], e2.x),
             add_rn(mul_rn(zsh[d0 + 12], e3.x), v0))));
        v1 = add_rn(mul_rn(zsh[d0 + 1], e0.y),
             add_rn(mul_rn(zsh[d0 + 5], e1.y),
             add_rn(mul_rn(zsh[d0 + 9], e2.y),
             add_rn(mul_rn(zsh[d0 + 13], e3.y), v1))));
        v2 = add_rn(mul_rn(zsh[d0 + 2], e0.z),
             add_rn(mul_rn(zsh[d0 + 6], e1.z),
             add_rn(mul_rn(zsh[d0 + 10], e2.z),
             add_rn(mul_rn(zsh[d0 + 14], e3.z), v2))));
        v3 = add_rn(mul_rn(zsh[d0 + 3], e0.w),
             add_rn(mul_rn(zsh[d0 + 7], e1.w),
             add_rn(mul_rn(zsh[d0 + 11], e2.w),
             add_rn(mul_rn(zsh[d0 + 15], e3.w), v3))));
    }
    return add_rn(add_rn(v0, v1), add_rn(v2, v3));
}

// ---------------------------------------------------------------------------
// merged prep: blocks 0-31 -> np ||e||^2 + zeroing; blocks 32-863 -> Bmat.
__global__ __launch_bounds__(256) void prep_kernel(const float* __restrict__ cb,
                                                   float* __restrict__ Bhat,
                                                   uint4* __restrict__ Bmat,
                                                   float* __restrict__ out,
                                                   int* __restrict__ cnt) {
    const int tid = threadIdx.x;
    if (blockIdx.x < 32) {
        int i = blockIdx.x * 256 + tid;       // 0..MM*NE-1
        if (i == 0) { out[LOSS_OFF] = 0.0f; cnt[0] = 0; cnt[1] = 0; }
        if (i < NE) out[BIN_OFF + i] = 0.0f;
        const float4* r4 = (const float4*)(cb + (size_t)i * ED);
        float x[ED];
#pragma unroll
        for (int q = 0; q < 16; ++q) {
            float4 v = r4[q];
            x[q*4+0] = v.x; x[q*4+1] = v.y; x[q*4+2] = v.z; x[q*4+3] = v.w;
        }
        Bhat[i] = np_sumsq64(x);
        return;
    }
    // Bmat build: t in [0, 8*13*2048)
    int t = (blockIdx.x - 32) * 256 + tid;
    int lane = t & 63;
    int ct = (t >> 6) & 31;
    int rem = t >> 11;
    int c = rem % 13;
    int m = rem / 13;
    int h = lane >> 5;
    int k = ct * 32 + (lane & 31);

    unsigned short v[8];
#pragma unroll
    for (int j = 0; j < 8; ++j) v[j] = 0;

    if (c < 12) {
        int d0 = 16 * (c & 3) + 8 * h;
        const float* e = cb + ((size_t)m * NE + k) * ED + d0;
#pragma unroll
        for (int j = 0; j < 8; ++j) {
            float f = -2.0f * e[j];
            unsigned short hi = f2bf(f);
            v[j] = (c >= 4 && c < 8) ? f2bf(f - bf2f(hi)) : hi;
        }
    } else if (h == 0) {
        const float* e = cb + ((size_t)m * NE + k) * ED;
        float s = 0.f;
#pragma unroll
        for (int d = 0; d < ED; ++d) s += e[d] * e[d];
        v[0] = f2bf(s);                       // + ||e||^2 (bf16; err ~4e-8)
        v[1] = 0x3F80;                        // + 1.0 shift
    }
    uint4 o;
    o.x = (unsigned)v[0] | ((unsigned)v[1] << 16);
    o.y = (unsigned)v[2] | ((unsigned)v[3] << 16);
    o.z = (unsigned)v[4] | ((unsigned)v[5] << 16);
    o.w = (unsigned)v[6] | ((unsigned)v[7] << 16);
    Bmat[t] = o;
}

// ---------------------------------------------------------------------------
// phase 1: split-bf16 MFMA distance + top-2 flag + candidate collection.
__global__ __launch_bounds__(512, 4) void argmin_kernel(
        const float* __restrict__ z, const uint4* __restrict__ Bmat,
        int* __restrict__ idx_out, int* __restrict__ cnt,
        int* __restrict__ list, int* __restrict__ candk,
        unsigned* __restrict__ candu) {
    const int tid = threadIdx.x;
    const int m = blockIdx.y;
    const int row0 = blockIdx.x * 256;
    const int w = tid >> 6;
    const int l = tid & 63;
    const int h = l >> 5;
    const int r5 = l & 31;

    __shared__ uint4 ldsB[2][13 * 2 * 64];    // 2 x 26 KB

    const int n_mine = row0 + w * 32 + r5;
    const int b = n_mine >> 10;
    const int hw = n_mine & (HWD - 1);
    const float* zbase = z + (((size_t)(b * CC + m * ED)) << 10) + hw;

    bf16x8 zh[4], zl[4];
#pragma unroll
    for (int i = 0; i < 4; ++i) {
        int o = 2 * i + h;
#pragma unroll
        for (int j = 0; j < 8; ++j) {
            float f = zbase[(size_t)(8 * o + j) << 10];
            unsigned short hb = f2bf(f);
            unsigned short lb = f2bf(f - bf2f(hb));
            zh[i][j] = (short)hb;
            zl[i][j] = (short)lb;
        }
    }
    bf16x8 ones12 = {0, 0, 0, 0, 0, 0, 0, 0};
    if (h == 0) { ones12[0] = (short)0x3F80; ones12[1] = (short)0x3F80; }

    unsigned rbm = 0xFFFFFFF0u, rsec = 0xFFFFFFFFu, rinfo = 0;
    // per-lane 6-slot candidate buffer (registers)
    int ccnt = 0;
    int k0 = -1, k1 = -1, k2 = -1, k3 = -1, k4 = -1, k5 = -1;
    unsigned u0 = 0, u1 = 0, u2 = 0, u3 = 0, u4 = 0, u5 = 0;

    auto stage = [&](int g, int bufi) {
        for (int seg = w; seg < 26; seg += 8) {
            int c = seg >> 1, ct2 = seg & 1;
            const uint4* src = Bmat +
                ((size_t)((m * 13 + c) * 32 + (g * 2 + ct2)) << 6) + l;
            uint4* dst = &ldsB[bufi][(c * 2 + ct2) * 64];
            __builtin_amdgcn_global_load_lds(
                (const __attribute__((address_space(1))) unsigned int*)src,
                (__attribute__((address_space(3))) unsigned int*)dst, 16, 0, 0);
        }
    };

    stage(0, 0);
    __syncthreads();
    int buf = 0;
    for (int g = 0; g < 16; ++g) {
        if (g < 15) stage(g + 1, buf ^ 1);

#pragma unroll
        for (int ctl = 0; ctl < 2; ++ctl) {
            f32x16 acc;
#pragma unroll
            for (int s = 0; s < 16; ++s) acc[s] = 0.0f;
#pragma unroll
            for (int c = 0; c < 13; ++c) {
                bf16x8 af = *(const bf16x8*)&ldsB[buf][(c * 2 + ctl) * 64 + l];
                bf16x8 bfr = (c < 8) ? zh[c & 3] : ((c < 12) ? zl[c & 3] : ones12);
                acc = __builtin_amdgcn_mfma_f32_32x32x16_bf16(af, bfr, acc, 0, 0, 0);
            }
            unsigned u[16];
#pragma unroll
            for (int s = 0; s < 16; ++s)
                u[s] = (__float_as_uint(acc[s]) & 0xFFFFFFF0u) | (unsigned)s;
            // top-2 tournament of 16
            unsigned b0 = umin_(u[0], u[1]),  s0 = umax_(u[0], u[1]);
            unsigned b1 = umin_(u[2], u[3]),  s1 = umax_(u[2], u[3]);
            unsigned b2 = umin_(u[4], u[5]),  s2 = umax_(u[4], u[5]);
            unsigned b3 = umin_(u[6], u[7]),  s3 = umax_(u[6], u[7]);
            unsigned b4 = umin_(u[8], u[9]),  s4 = umax_(u[8], u[9]);
            unsigned b5 = umin_(u[10], u[11]), s5 = umax_(u[10], u[11]);
            unsigned b6 = umin_(u[12], u[13]), s6 = umax_(u[12], u[13]);
            unsigned b7 = umin_(u[14], u[15]), s7 = umax_(u[14], u[15]);
            unsigned B0 = umin_(b0, b1), S0 = umin3(umax_(b0, b1), s0, s1);
            unsigned B1 = umin_(b2, b3), S1 = umin3(umax_(b2, b3), s2, s3);
            unsigned B2 = umin_(b4, b5), S2 = umin3(umax_(b4, b5), s4, s5);
            unsigned B3 = umin_(b6, b7), S3 = umin3(umax_(b6, b7), s6, s7);
            unsigned C0 = umin_(B0, B1), T0 = umin3(umax_(B0, B1), S0, S1);
            unsigned C1 = umin_(B2, B3), T1 = umin3(umax_(B2, B3), S2, S3);
            unsigned bt = umin_(C0, C1), st = umin3(umax_(C0, C1), T0, T1);

            unsigned tile = (unsigned)(g * 2 + ctl);
            bool take = bt < rbm;
            unsigned other = take ? rbm : bt;
            rsec = umin3(rsec, st, other);
            unsigned newinfo = (tile << 4) | (bt & 15u);
            rbm = take ? bt : rbm;
            rinfo = take ? newinfo : rinfo;

            // candidate collection: rbm is post-update -> window covers final
            unsigned limit = rbm + UWIN;
            if (bt < limit) {
#pragma unroll
                for (int s = 0; s < 16; ++s) {
                    if (u[s] < limit) {
                        int kc = (int)(tile * 32u + ((unsigned)s & 3u) +
                                       8u * ((unsigned)s >> 2) + 4u * (unsigned)h);
                        unsigned uu = u[s];
                        if (ccnt == 0) { k0 = kc; u0 = uu; }
                        else if (ccnt == 1) { k1 = kc; u1 = uu; }
                        else if (ccnt == 2) { k2 = kc; u2 = uu; }
                        else if (ccnt == 3) { k3 = kc; u3 = uu; }
                        else if (ccnt == 4) { k4 = kc; u4 = uu; }
                        else if (ccnt == 5) { k5 = kc; u5 = uu; }
                        ccnt++;
                    }
                }
            }
        }
        __syncthreads();
        buf ^= 1;
    }

    // partner-half candidate exchange (unconditional shfls)
    int pcnt = __shfl_xor(ccnt, 32, 64);
    int pk0 = __shfl_xor(k0, 32, 64), pk1 = __shfl_xor(k1, 32, 64);
    int pk2 = __shfl_xor(k2, 32, 64), pk3 = __shfl_xor(k3, 32, 64);
    int pk4 = __shfl_xor(k4, 32, 64), pk5 = __shfl_xor(k5, 32, 64);
    unsigned pu0 = __shfl_xor(u0, 32, 64), pu1 = __shfl_xor(u1, 32, 64);
    unsigned pu2 = __shfl_xor(u2, 32, 64), pu3 = __shfl_xor(u3, 32, 64);
    unsigned pu4 = __shfl_xor(u4, 32, 64), pu5 = __shfl_xor(u5, 32, 64);

    // decode k, merge h-halves, write
    unsigned ss = rinfo & 15u, tile = rinfo >> 4;
    int k = (int)(tile * 32 + (ss & 3u) + 8u * (ss >> 2) + 4u * (unsigned)h);
    unsigned orbm = __shfl_xor(rbm, 32, 64);
    int ok = __shfl_xor(k, 32, 64);
    unsigned orsec = __shfl_xor(rsec, 32, 64);
    bool take = orbm < rbm;
    unsigned lose = take ? rbm : orbm;
    unsigned fb = take ? orbm : rbm;
    int fk = take ? ok : k;
    unsigned fs = umin3(rsec, orsec, lose);
    if (l < 32) {
        int mn = m * NN + n_mine;
        idx_out[mn] = fk;
        float margin = __uint_as_float(fs & 0xFFFFFFF0u) -
                       __uint_as_float(fb & 0xFFFFFFF0u);
        if (margin < TAU) {
            int p = atomicAdd(cnt, 1);
            if (p < 32768) {
                list[p] = mn;
                int* ck = candk + p * 12;
                unsigned* cu = candu + p * 12;
                if (ccnt > 6 || pcnt > 6) {
                    ck[0] = -2;   // overflow sentinel -> fallback full scan
                } else {
                    ck[0] = (ccnt > 0) ? k0 : -1;  cu[0] = u0;
                    ck[1] = (ccnt > 1) ? k1 : -1;  cu[1] = u1;
                    ck[2] = (ccnt > 2) ? k2 : -1;  cu[2] = u2;
                    ck[3] = (ccnt > 3) ? k3 : -1;  cu[3] = u3;
                    ck[4] = (ccnt > 4) ? k4 : -1;  cu[4] = u4;
                    ck[5] = (ccnt > 5) ? k5 : -1;  cu[5] = u5;
                    ck[6] = (pcnt > 0) ? pk0 : -1; cu[6] = pu0;
                    ck[7] = (pcnt > 1) ? pk1 : -1; cu[7] = pu1;
                    ck[8] = (pcnt > 2) ? pk2 : -1; cu[8] = pu2;
                    ck[9] = (pcnt > 3) ? pk3 : -1; cu[9] = pu3;
                    ck[10] = (pcnt > 4) ? pk4 : -1; cu[10] = pu4;
                    ck[11] = (pcnt > 5) ? pk5 : -1; cu[11] = pu5;
                }
            }
        }
    }
}

// ---------------------------------------------------------------------------
// phase 2a: exact np emulation on collected candidates. One WAVE per row.
__global__ __launch_bounds__(256) void cand_kernel(
        const float* __restrict__ z, const float* __restrict__ cb,
        const float* __restrict__ Bhat, int* __restrict__ cnt,
        const int* __restrict__ list, const int* __restrict__ candk,
        const unsigned* __restrict__ candu, int* __restrict__ idx_out,
        int* __restrict__ oflist) {
    const int tid = threadIdx.x;
    const int lane = tid & 63;
    const int wv = tid >> 6;
    const int wid = (blockIdx.x * 256 + tid) >> 6;
    const int nw = gridDim.x * 4;
    const int total = cnt[0] < 32768 ? cnt[0] : 32768;

    __shared__ float zsh[4][ED];

    for (int r = wid; r < total; r += nw) {
        const int mn = list[r];
        const int sent = candk[r * 12];       // broadcast read
        if (sent == -2) {                      // overflow -> fallback list
            if (lane == 0) {
                int q = atomicAdd(cnt + 1, 1);
                if (q < 8192) oflist[q] = mn;
            }
            continue;
        }
        const int m = mn >> 14;
        const int n = mn & (NN - 1);
        const int b = n >> 10;
        const int hw = n & (HWD - 1);

        // stage z row (lane = d), wave-local
        zsh[wv][lane] = z[(((size_t)(b * CC + m * ED + lane)) << 10) + hw];

        int kj = (lane < 12) ? candk[r * 12 + lane] : -1;
        unsigned uj = (lane < 12 && kj >= 0) ? candu[r * 12 + lane] : 0xFFFFFFFFu;

        unsigned fbu = uj;
#pragma unroll
        for (int off = 32; off >= 1; off >>= 1)
            fbu = umin_(fbu, (unsigned)__shfl_xor((int)fbu, off, 64));

        bool active = (kj >= 0) && (uj <= fbu + UWIN);

        float A = np_sumsq64(&zsh[wv][0]);

        float dref = FLT_MAX;
        if (active) {
            const float4* cr4 = (const float4*)(cb + ((size_t)m * NE + kj) * ED);
            float C = np_dot64(&zsh[wv][0], cr4);
            dref = sub_rn(add_rn(A, Bhat[m * NE + kj]), mul_rn(2.0f, C));
        }
        int kk = active ? kj : NE;
#pragma unroll
        for (int off = 32; off >= 1; off >>= 1) {
            float ov = __shfl_down(dref, off, 64);
            int oi = __shfl_down(kk, off, 64);
            if (ov < dref || (ov == dref && oi < kk)) { dref = ov; kk = oi; }
        }
        if (lane == 0) idx_out[mn] = kk;
    }
}

// ---------------------------------------------------------------------------
// phase 2b: fallback full-scan exact emulation (overflow rows; ~0 expected).
__global__ __launch_bounds__(256) void emul_kernel(
        const float* __restrict__ z, const float* __restrict__ cb,
        const float* __restrict__ Bhat, const int* __restrict__ cnt,
        const int* __restrict__ oflist, int* __restrict__ idx_out) {
    const int tid = threadIdx.x;
    const int lane = tid & 63;
    const int w = tid >> 6;
    const int total = cnt[1] < 8192 ? cnt[1] : 8192;

    __shared__ float zsh[ED];
    __shared__ float rbest[4];
    __shared__ int ridx[4];

    for (int r = blockIdx.x; r < total; r += gridDim.x) {
        const int mn = oflist[r];
        const int m = mn >> 14;
        const int n = mn & (NN - 1);
        const int b = n >> 10;
        const int hw = n & (HWD - 1);

        __syncthreads();
        if (tid < ED) {
            const float* zbase = z + (((size_t)(b * CC + m * ED)) << 10) + hw;
            zsh[tid] = zbase[(size_t)tid << 10];
        }
        __syncthreads();

        const float A = np_sumsq64(zsh);
        const float* cbm = cb + (size_t)m * NE * ED;
        const float* Bm = Bhat + m * NE;
        float best = FLT_MAX;
        int bidx = NE;
#pragma unroll
        for (int kk = 0; kk < 4; ++kk) {
            const int k = kk * 256 + tid;
            const float4* cr4 = (const float4*)(cbm + (size_t)k * ED);
            float C = np_dot64(zsh, cr4);
            float dk = sub_rn(add_rn(A, Bm[k]), mul_rn(2.0f, C));
            if (dk < best || (dk == best && k < bidx)) { best = dk; bidx = k; }
        }
#pragma unroll
        for (int off = 32; off >= 1; off >>= 1) {
            float ov = __shfl_down(best, off, 64);
            int oi = __shfl_down(bidx, off, 64);
            if (ov < best || (ov == best && oi < bidx)) { best = ov; bidx = oi; }
        }
        if (lane == 0) { rbest[w] = best; ridx[w] = bidx; }
        __syncthreads();
        if (tid == 0) {
            float bb = rbest[0]; int bi = ridx[0];
#pragma unroll
            for (int i = 1; i < 4; ++i) {
                if (rbest[i] < bb || (rbest[i] == bb && ridx[i] < bi)) {
                    bb = rbest[i]; bi = ridx[i];
                }
            }
            idx_out[mn] = bi;
        }
    }
}

// ---------------------------------------------------------------------------
// Outputs: z_vq gather-scatter, indices as float, loss reduction, histogram.
__global__ __launch_bounds__(256) void output_kernel(
        const float* __restrict__ z, const float* __restrict__ cb,
        const int* __restrict__ idx_in, float* __restrict__ out) {
    const int tid = threadIdx.x;
    const int n = blockIdx.x * 256 + tid;
    const int m = blockIdx.y;
    const int b = n >> 10;
    const int hw = n & (HWD - 1);
    const int idx = idx_in[m * NN + n];

    out[IDX_OFF + m * NN + n] = (float)idx;

    const float* cr = cb + ((size_t)m * NE + (size_t)idx) * ED;
    const float* zbase = z + (((size_t)(b * CC + m * ED)) << 10) + hw;
    float* ob = out + (((size_t)(b * CC + m * ED)) << 10) + hw;

    double acc = 0.0;
#pragma unroll
    for (int d = 0; d < ED; ++d) {
        float c = cr[d];
        float zv = zbase[(size_t)d << 10];
        ob[(size_t)d << 10] = c;
        float diff = c - zv;
        acc += (double)diff * (double)diff;
    }

    __shared__ int hist[NE];
#pragma unroll
    for (int i = 0; i < 4; ++i) hist[tid + i * 256] = 0;
    __syncthreads();
    atomicAdd(&hist[idx], 1);

#pragma unroll
    for (int off = 32; off >= 1; off >>= 1)
        acc += __shfl_down(acc, off, 64);
    __shared__ double wsum[4];
    if ((tid & 63) == 0) wsum[tid >> 6] = acc;
    __syncthreads();
    if (tid == 0) {
        double t = wsum[0] + wsum[1] + wsum[2] + wsum[3];
        atomicAdd(out + LOSS_OFF, (float)(t * (1.25 / 1048576.0)));
    }
#pragma unroll
    for (int i = 0; i < 4; ++i) {
        int v = hist[tid + i * 256];
        if (v) atomicAdd(out + BIN_OFF + tid + i * 256, (float)v);
    }
}

// ---------------------------------------------------------------------------
extern "C" void kernel_launch(void* const* d_in, const int* in_sizes, int n_in,
                              void* d_out, int out_size, void* d_ws, size_t ws_size,
                              hipStream_t stream) {
    const float* z = (const float*)d_in[0];    // (16,512,32,32) fp32
    const float* cb = (const float*)d_in[1];   // (8,1024,64) fp32
    float* out = (float*)d_out;
    char* ws = (char*)d_ws;
    float* Bhat = (float*)(ws + WS_B);
    int* idxw = (int*)(ws + WS_IDX);
    int* cnt = (int*)(ws + WS_CNT);
    int* list = (int*)(ws + WS_LIST);
    int* oflist = (int*)(ws + WS_OF);
    int* candk = (int*)(ws + WS_CANDK);
    unsigned* candu = (unsigned*)(ws + WS_CANDU);
    uint4* Bmat = (uint4*)(ws + WS_BMAT);

    prep_kernel<<<dim3(864), dim3(256), 0, stream>>>(cb, Bhat, Bmat, out, cnt);
    argmin_kernel<<<dim3(NN / 256, MM), dim3(512), 0, stream>>>(
        z, Bmat, idxw, cnt, list, candk, candu);
    cand_kernel<<<dim3(256), dim3(256), 0, stream>>>(
        z, cb, Bhat, cnt, list, candk, candu, idxw, oflist);
    emul_kernel<<<dim3(256), dim3(256), 0, stream>>>(
        z, cb, Bhat, cnt, oflist, idxw);
    output_kernel<<<dim3(NN / 256, MM), dim3(256), 0, stream>>>(z, cb, idxw, out);
}

// Round 7
// 191.628 us; speedup vs baseline: 1.5223x; 1.5223x over previous
//
#include <hip/hip_runtime.h>
#include <cfloat>

// Problem constants
#define BS 16
#define CC 512
#define HWD 1024      // h*w
#define NN 16384      // BS*HWD rows
#define MM 8          // sub-codebooks
#define NE 1024       // codes per sub-codebook
#define ED 64         // code dim

// d_out layout (all read back as float32):
#define LOSS_OFF 8388608
#define IDX_OFF  8388609
#define BIN_OFF  8519681

// flag margin: ref fp32 quantization perturbs d by <=~1.5e-5; phase-1 err ~3e-6
#define TAU 4e-5f
// candidate window in raw float-bit units (>= 2.38e-5 in value space)
#define UWIN 400u

// workspace byte offsets (end == 7,274,528 B, same ceiling as round 5)
#define WS_B     0            // float[MM*NE] emulated np ||e||^2        (32 KB)
#define WS_IDX   32768        // int[MM*NN]                              (512 KB)
#define WS_CNT   557056       // int[2]: flag count, overflow count (+pad)
#define WS_LIST  557088       // int[32768] packed flagged rows          (128 KB)
#define WS_OF    688160       // int[8192] overflow rows                 (32 KB)
#define WS_CAND  720928       // ushort[MM*NN*2*6] candidate ids         (3 MB)
#define WS_BMAT  3866656      // uint4[8*13*32*64] bf16 frag-order B     (3.25 MB)

typedef __attribute__((ext_vector_type(8))) short bf16x8;
typedef __attribute__((ext_vector_type(16))) float f32x16;

// ---- bf16 helpers ---------------------------------------------------------
__device__ __forceinline__ unsigned short f2bf(float f) {
    unsigned int u = __float_as_uint(f);
    unsigned int r = (u + 0x7fffu + ((u >> 16) & 1u)) >> 16;
    return (unsigned short)r;
}
__device__ __forceinline__ float bf2f(unsigned short h) {
    return __uint_as_float(((unsigned int)h) << 16);
}
__device__ __forceinline__ unsigned umin_(unsigned a, unsigned b) { return a < b ? a : b; }
__device__ __forceinline__ unsigned umax_(unsigned a, unsigned b) { return a > b ? a : b; }
__device__ __forceinline__ unsigned umin3(unsigned a, unsigned b, unsigned c) {
    return umin_(umin_(a, b), c);
}

// ---- fp32 ops with contraction disabled -----------------------------------
__device__ __forceinline__ float mul_rn(float a, float b) {
#pragma clang fp contract(off)
    return a * b;
}
__device__ __forceinline__ float add_rn(float a, float b) {
#pragma clang fp contract(off)
    return a + b;
}
__device__ __forceinline__ float sub_rn(float a, float b) {
#pragma clang fp contract(off)
    return a - b;
}

// numpy FLOAT_pairwise_sum over fl(x_d^2), n=64
__device__ __forceinline__ float np_sumsq64(const float* x) {
    float r[8];
#pragma unroll
    for (int j = 0; j < 8; ++j) r[j] = mul_rn(x[j], x[j]);
#pragma unroll
    for (int i = 8; i < 64; i += 8) {
#pragma unroll
        for (int j = 0; j < 8; ++j) r[j] = add_rn(r[j], mul_rn(x[i + j], x[i + j]));
    }
    return add_rn(add_rn(add_rn(r[0], r[1]), add_rn(r[2], r[3])),
                  add_rn(add_rn(r[4], r[5]), add_rn(r[6], r[7])));
}

// numpy einsum sum_of_products_contig_two, SSE npyv (no FMA); z from LDS ptr
__device__ __forceinline__ float np_dot64(const float* zsh, const float4* cr4) {
    float v0 = 0.f, v1 = 0.f, v2 = 0.f, v3 = 0.f;
#pragma unroll
    for (int t = 0; t < 4; ++t) {
        float4 e0 = cr4[t * 4 + 0];
        float4 e1 = cr4[t * 4 + 1];
        float4 e2 = cr4[t * 4 + 2];
        float4 e3 = cr4[t * 4 + 3];
        const int d0 = 16 * t;
        v0 = add_rn(mul_rn(zsh[d0 + 0], e0.x),
             add_rn(mul_rn(zsh[d0 + 4], e1.x),
             add_rn(mul_rn(zsh[d0 + 8], e2.x),
             add_rn(mul_rn(zsh[d0 + 12], e3.x), v0))));
        v1 = add_rn(mul_rn(zsh[d0 + 1], e0.y),
             add_rn(mul_rn(zsh[d0 + 5], e1.y),
             add_rn(mul_rn(zsh[d0 + 9], e2.y),
             add_rn(mul_rn(zsh[d0 + 13], e3.y), v1))));
        v2 = add_rn(mul_rn(zsh[d0 + 2], e0.z),
             add_rn(mul_rn(zsh[d0 + 6], e1.z),
             add_rn(mul_rn(zsh[d0 + 10], e2.z),
             add_rn(mul_rn(zsh[d0 + 14], e3.z), v2))));
        v3 = add_rn(mul_rn(zsh[d0 + 3], e0.w),
             add_rn(mul_rn(zsh[d0 + 7], e1.w),
             add_rn(mul_rn(zsh[d0 + 11], e2.w),
             add_rn(mul_rn(zsh[d0 + 15], e3.w), v3))));
    }
    return add_rn(add_rn(v0, v1), add_rn(v2, v3));
}

// ---------------------------------------------------------------------------
// merged prep: blocks 0-31 -> np ||e||^2 + zeroing; blocks 32-863 -> Bmat.
__global__ __launch_bounds__(256) void prep_kernel(const float* __restrict__ cb,
                                                   float* __restrict__ Bhat,
                                                   uint4* __restrict__ Bmat,
                                                   float* __restrict__ out,
                                                   int* __restrict__ cnt) {
    const int tid = threadIdx.x;
    if (blockIdx.x < 32) {
        int i = blockIdx.x * 256 + tid;       // 0..MM*NE-1
        if (i == 0) { out[LOSS_OFF] = 0.0f; cnt[0] = 0; cnt[1] = 0; }
        if (i < NE) out[BIN_OFF + i] = 0.0f;
        const float4* r4 = (const float4*)(cb + (size_t)i * ED);
        float x[ED];
#pragma unroll
        for (int q = 0; q < 16; ++q) {
            float4 v = r4[q];
            x[q*4+0] = v.x; x[q*4+1] = v.y; x[q*4+2] = v.z; x[q*4+3] = v.w;
        }
        Bhat[i] = np_sumsq64(x);
        return;
    }
    // Bmat build: t in [0, 8*13*2048)
    int t = (blockIdx.x - 32) * 256 + tid;
    int lane = t & 63;
    int ct = (t >> 6) & 31;
    int rem = t >> 11;
    int c = rem % 13;
    int m = rem / 13;
    int h = lane >> 5;
    int k = ct * 32 + (lane & 31);

    unsigned short v[8];
#pragma unroll
    for (int j = 0; j < 8; ++j) v[j] = 0;

    if (c < 12) {
        int d0 = 16 * (c & 3) + 8 * h;
        const float* e = cb + ((size_t)m * NE + k) * ED + d0;
#pragma unroll
        for (int j = 0; j < 8; ++j) {
            float f = -2.0f * e[j];
            unsigned short hi = f2bf(f);
            v[j] = (c >= 4 && c < 8) ? f2bf(f - bf2f(hi)) : hi;
        }
    } else if (h == 0) {
        const float* e = cb + ((size_t)m * NE + k) * ED;
        float s = 0.f;
#pragma unroll
        for (int d = 0; d < ED; ++d) s += e[d] * e[d];
        v[0] = f2bf(s);                       // + ||e||^2 (bf16; err ~4e-8)
        v[1] = 0x3F80;                        // + 1.0 shift
    }
    uint4 o;
    o.x = (unsigned)v[0] | ((unsigned)v[1] << 16);
    o.y = (unsigned)v[2] | ((unsigned)v[3] << 16);
    o.z = (unsigned)v[4] | ((unsigned)v[5] << 16);
    o.w = (unsigned)v[6] | ((unsigned)v[7] << 16);
    Bmat[t] = o;
}

// ---------------------------------------------------------------------------
// phase 1: split-bf16 MFMA distance + top-2 flag + candidate collection.
// Candidates stream straight to global ushort slots (no register buffer —
// round 6's register buffer caused a 172 MB scratch-spill regression).
__global__ __launch_bounds__(512, 4) void argmin_kernel(
        const float* __restrict__ z, const uint4* __restrict__ Bmat,
        int* __restrict__ idx_out, int* __restrict__ cnt,
        int* __restrict__ list, unsigned short* __restrict__ cand) {
    const int tid = threadIdx.x;
    const int m = blockIdx.y;
    const int row0 = blockIdx.x * 256;
    const int w = tid >> 6;
    const int l = tid & 63;
    const int h = l >> 5;
    const int r5 = l & 31;

    __shared__ uint4 ldsB[2][13 * 2 * 64];    // 2 x 26 KB

    const int n_mine = row0 + w * 32 + r5;
    const int b = n_mine >> 10;
    const int hw = n_mine & (HWD - 1);
    const float* zbase = z + (((size_t)(b * CC + m * ED)) << 10) + hw;

    bf16x8 zh[4], zl[4];
#pragma unroll
    for (int i = 0; i < 4; ++i) {
        int o = 2 * i + h;
#pragma unroll
        for (int j = 0; j < 8; ++j) {
            float f = zbase[(size_t)(8 * o + j) << 10];
            unsigned short hb = f2bf(f);
            unsigned short lb = f2bf(f - bf2f(hb));
            zh[i][j] = (short)hb;
            zl[i][j] = (short)lb;
        }
    }
    bf16x8 ones12 = {0, 0, 0, 0, 0, 0, 0, 0};
    if (h == 0) { ones12[0] = (short)0x3F80; ones12[1] = (short)0x3F80; }

    unsigned rbm = 0xFFFFFFF0u, rsec = 0xFFFFFFFFu, rinfo = 0;
    int ccnt = 0;
    unsigned short* myslots = cand + ((size_t)(m * NN + n_mine) * 2 + h) * 6;

    auto stage = [&](int g, int bufi) {
        for (int seg = w; seg < 26; seg += 8) {
            int c = seg >> 1, ct2 = seg & 1;
            const uint4* src = Bmat +
                ((size_t)((m * 13 + c) * 32 + (g * 2 + ct2)) << 6) + l;
            uint4* dst = &ldsB[bufi][(c * 2 + ct2) * 64];
            __builtin_amdgcn_global_load_lds(
                (const __attribute__((address_space(1))) unsigned int*)src,
                (__attribute__((address_space(3))) unsigned int*)dst, 16, 0, 0);
        }
    };

    stage(0, 0);
    __syncthreads();
    int buf = 0;
    for (int g = 0; g < 16; ++g) {
        if (g < 15) stage(g + 1, buf ^ 1);

#pragma unroll
        for (int ctl = 0; ctl < 2; ++ctl) {
            f32x16 acc;
#pragma unroll
            for (int s = 0; s < 16; ++s) acc[s] = 0.0f;
#pragma unroll
            for (int c = 0; c < 13; ++c) {
                bf16x8 af = *(const bf16x8*)&ldsB[buf][(c * 2 + ctl) * 64 + l];
                bf16x8 bfr = (c < 8) ? zh[c & 3] : ((c < 12) ? zl[c & 3] : ones12);
                acc = __builtin_amdgcn_mfma_f32_32x32x16_bf16(af, bfr, acc, 0, 0, 0);
            }
            unsigned u[16];
#pragma unroll
            for (int s = 0; s < 16; ++s)
                u[s] = (__float_as_uint(acc[s]) & 0xFFFFFFF0u) | (unsigned)s;
            // top-2 tournament of 16
            unsigned b0 = umin_(u[0], u[1]),  s0 = umax_(u[0], u[1]);
            unsigned b1 = umin_(u[2], u[3]),  s1 = umax_(u[2], u[3]);
            unsigned b2 = umin_(u[4], u[5]),  s2 = umax_(u[4], u[5]);
            unsigned b3 = umin_(u[6], u[7]),  s3 = umax_(u[6], u[7]);
            unsigned b4 = umin_(u[8], u[9]),  s4 = umax_(u[8], u[9]);
            unsigned b5 = umin_(u[10], u[11]), s5 = umax_(u[10], u[11]);
            unsigned b6 = umin_(u[12], u[13]), s6 = umax_(u[12], u[13]);
            unsigned b7 = umin_(u[14], u[15]), s7 = umax_(u[14], u[15]);
            unsigned B0 = umin_(b0, b1), S0 = umin3(umax_(b0, b1), s0, s1);
            unsigned B1 = umin_(b2, b3), S1 = umin3(umax_(b2, b3), s2, s3);
            unsigned B2 = umin_(b4, b5), S2 = umin3(umax_(b4, b5), s4, s5);
            unsigned B3 = umin_(b6, b7), S3 = umin3(umax_(b6, b7), s6, s7);
            unsigned C0 = umin_(B0, B1), T0 = umin3(umax_(B0, B1), S0, S1);
            unsigned C1 = umin_(B2, B3), T1 = umin3(umax_(B2, B3), S2, S3);
            unsigned bt = umin_(C0, C1), st = umin3(umax_(C0, C1), T0, T1);

            unsigned tile = (unsigned)(g * 2 + ctl);
            unsigned oldrbm = rbm;
            bool take = bt < oldrbm;
            // reset: new record beats old by > UWIN -> all stored cands have
            // u >= rbm_at_store >= oldrbm > bt+UWIN >= fb+UWIN: disqualified.
            if (take && bt + UWIN < oldrbm) ccnt = 0;
            unsigned other = take ? oldrbm : bt;
            rsec = umin3(rsec, st, other);
            rbm = take ? bt : oldrbm;
            rinfo = take ? ((tile << 4) | (bt & 15u)) : rinfo;

            unsigned limit = rbm + UWIN;   // rbm post-update: covers final window
            if (bt < limit) {
#pragma unroll
                for (int s = 0; s < 16; ++s) {
                    if (u[s] < limit) {
                        if (ccnt < 6)
                            myslots[ccnt] = (unsigned short)(
                                tile * 32u + ((unsigned)s & 3u) +
                                8u * ((unsigned)s >> 2) + 4u * (unsigned)h);
                        ccnt++;
                    }
                }
            }
        }
        __syncthreads();
        buf ^= 1;
    }

    int pcnt = __shfl_xor(ccnt, 32, 64);

    // decode k, merge h-halves, write
    unsigned ss = rinfo & 15u, tile = rinfo >> 4;
    int k = (int)(tile * 32 + (ss & 3u) + 8u * (ss >> 2) + 4u * (unsigned)h);
    unsigned orbm = __shfl_xor(rbm, 32, 64);
    int ok = __shfl_xor(k, 32, 64);
    unsigned orsec = __shfl_xor(rsec, 32, 64);
    bool take = orbm < rbm;
    unsigned lose = take ? rbm : orbm;
    unsigned fb = take ? orbm : rbm;
    int fk = take ? ok : k;
    unsigned fs = umin3(rsec, orsec, lose);
    if (l < 32) {
        int mn = m * NN + n_mine;
        idx_out[mn] = fk;
        float margin = __uint_as_float(fs & 0xFFFFFFF0u) -
                       __uint_as_float(fb & 0xFFFFFFF0u);
        if (margin < TAU) {
            int p = atomicAdd(cnt, 1);
            if (p < 32768) {
                int c0 = ccnt > 6 ? 7 : ccnt;   // 7 = overflow sentinel
                int c1 = pcnt > 6 ? 7 : pcnt;
                list[p] = mn | (c0 << 20) | (c1 << 24);
            }
        }
    }
}

// ---------------------------------------------------------------------------
// phase 2a: exact np emulation on collected candidates. One WAVE per row.
__global__ __launch_bounds__(256) void cand_kernel(
        const float* __restrict__ z, const float* __restrict__ cb,
        const float* __restrict__ Bhat, int* __restrict__ cnt,
        const int* __restrict__ list, const unsigned short* __restrict__ cand,
        int* __restrict__ idx_out, int* __restrict__ oflist) {
    const int tid = threadIdx.x;
    const int lane = tid & 63;
    const int wv = tid >> 6;
    const int wid = (blockIdx.x * 256 + tid) >> 6;
    const int nw = gridDim.x * 4;
    const int total = cnt[0] < 32768 ? cnt[0] : 32768;

    __shared__ float zsh[4][ED];

    for (int r = wid; r < total; r += nw) {
        const int e = list[r];
        const int mn = e & 0xFFFFF;
        const int c0 = (e >> 20) & 15;
        const int c1 = (e >> 24) & 15;
        if (c0 == 7 || c1 == 7) {              // overflow -> fallback list
            if (lane == 0) {
                int q = atomicAdd(cnt + 1, 1);
                if (q < 8192) oflist[q] = mn;
            }
            continue;
        }
        const int m = mn >> 14;
        const int n = mn & (NN - 1);
        const int b = n >> 10;
        const int hw = n & (HWD - 1);

        // stage z row (lane = d), wave-local
        zsh[wv][lane] = z[(((size_t)(b * CC + m * ED + lane)) << 10) + hw];

        int kj = -1;
        if (lane < c0) kj = cand[(size_t)mn * 12 + lane];
        else if (lane >= 8 && lane < 8 + c1) kj = cand[(size_t)mn * 12 + 6 + (lane - 8)];

        float A = np_sumsq64(&zsh[wv][0]);

        float dref = FLT_MAX;
        if (kj >= 0) {
            const float4* cr4 = (const float4*)(cb + ((size_t)m * NE + kj) * ED);
            float C = np_dot64(&zsh[wv][0], cr4);
            dref = sub_rn(add_rn(A, Bhat[m * NE + kj]), mul_rn(2.0f, C));
        }
        int kk = (kj >= 0) ? kj : NE;
#pragma unroll
        for (int off = 32; off >= 1; off >>= 1) {
            float ov = __shfl_down(dref, off, 64);
            int oi = __shfl_down(kk, off, 64);
            if (ov < dref || (ov == dref && oi < kk)) { dref = ov; kk = oi; }
        }
        if (lane == 0) idx_out[mn] = kk;
    }
}

// ---------------------------------------------------------------------------
// phase 2b: fallback full-scan exact emulation (overflow rows; ~0 expected).
__global__ __launch_bounds__(256) void emul_kernel(
        const float* __restrict__ z, const float* __restrict__ cb,
        const float* __restrict__ Bhat, const int* __restrict__ cnt,
        const int* __restrict__ oflist, int* __restrict__ idx_out) {
    const int tid = threadIdx.x;
    const int lane = tid & 63;
    const int w = tid >> 6;
    const int total = cnt[1] < 8192 ? cnt[1] : 8192;

    __shared__ float zsh[ED];
    __shared__ float rbest[4];
    __shared__ int ridx[4];

    for (int r = blockIdx.x; r < total; r += gridDim.x) {
        const int mn = oflist[r];
        const int m = mn >> 14;
        const int n = mn & (NN - 1);
        const int b = n >> 10;
        const int hw = n & (HWD - 1);

        __syncthreads();
        if (tid < ED) {
            const float* zbase = z + (((size_t)(b * CC + m * ED)) << 10) + hw;
            zsh[tid] = zbase[(size_t)tid << 10];
        }
        __syncthreads();

        const float A = np_sumsq64(zsh);
        const float* cbm = cb + (size_t)m * NE * ED;
        const float* Bm = Bhat + m * NE;
        float best = FLT_MAX;
        int bidx = NE;
#pragma unroll
        for (int kk = 0; kk < 4; ++kk) {
            const int k = kk * 256 + tid;
            const float4* cr4 = (const float4*)(cbm + (size_t)k * ED);
            float C = np_dot64(zsh, cr4);
            float dk = sub_rn(add_rn(A, Bm[k]), mul_rn(2.0f, C));
            if (dk < best || (dk == best && k < bidx)) { best = dk; bidx = k; }
        }
#pragma unroll
        for (int off = 32; off >= 1; off >>= 1) {
            float ov = __shfl_down(best, off, 64);
            int oi = __shfl_down(bidx, off, 64);
            if (ov < best || (ov == best && oi < bidx)) { best = ov; bidx = oi; }
        }
        if (lane == 0) { rbest[w] = best; ridx[w] = bidx; }
        __syncthreads();
        if (tid == 0) {
            float bb = rbest[0]; int bi = ridx[0];
#pragma unroll
            for (int i = 1; i < 4; ++i) {
                if (rbest[i] < bb || (rbest[i] == bb && ridx[i] < bi)) {
                    bb = rbest[i]; bi = ridx[i];
                }
            }
            idx_out[mn] = bi;
        }
    }
}

// ---------------------------------------------------------------------------
// Outputs: z_vq gather-scatter, indices as float, loss reduction, histogram.
__global__ __launch_bounds__(256) void output_kernel(
        const float* __restrict__ z, const float* __restrict__ cb,
        const int* __restrict__ idx_in, float* __restrict__ out) {
    const int tid = threadIdx.x;
    const int n = blockIdx.x * 256 + tid;
    const int m = blockIdx.y;
    const int b = n >> 10;
    const int hw = n & (HWD - 1);
    const int idx = idx_in[m * NN + n];

    out[IDX_OFF + m * NN + n] = (float)idx;

    const float* cr = cb + ((size_t)m * NE + (size_t)idx) * ED;
    const float* zbase = z + (((size_t)(b * CC + m * ED)) << 10) + hw;
    float* ob = out + (((size_t)(b * CC + m * ED)) << 10) + hw;

    double acc = 0.0;
#pragma unroll
    for (int d = 0; d < ED; ++d) {
        float c = cr[d];
        float zv = zbase[(size_t)d << 10];
        ob[(size_t)d << 10] = c;
        float diff = c - zv;
        acc += (double)diff * (double)diff;
    }

    __shared__ int hist[NE];
#pragma unroll
    for (int i = 0; i < 4; ++i) hist[tid + i * 256] = 0;
    __syncthreads();
    atomicAdd(&hist[idx], 1);

#pragma unroll
    for (int off = 32; off >= 1; off >>= 1)
        acc += __shfl_down(acc, off, 64);
    __shared__ double wsum[4];
    if ((tid & 63) == 0) wsum[tid >> 6] = acc;
    __syncthreads();
    if (tid == 0) {
        double t = wsum[0] + wsum[1] + wsum[2] + wsum[3];
        atomicAdd(out + LOSS_OFF, (float)(t * (1.25 / 1048576.0)));
    }
#pragma unroll
    for (int i = 0; i < 4; ++i) {
        int v = hist[tid + i * 256];
        if (v) atomicAdd(out + BIN_OFF + tid + i * 256, (float)v);
    }
}

// ---------------------------------------------------------------------------
extern "C" void kernel_launch(void* const* d_in, const int* in_sizes, int n_in,
                              void* d_out, int out_size, void* d_ws, size_t ws_size,
                              hipStream_t stream) {
    const float* z = (const float*)d_in[0];    // (16,512,32,32) fp32
    const float* cb = (const float*)d_in[1];   // (8,1024,64) fp32
    float* out = (float*)d_out;
    char* ws = (char*)d_ws;
    float* Bhat = (float*)(ws + WS_B);
    int* idxw = (int*)(ws + WS_IDX);
    int* cnt = (int*)(ws + WS_CNT);
    int* list = (int*)(ws + WS_LIST);
    int* oflist = (int*)(ws + WS_OF);
    unsigned short* cand = (unsigned short*)(ws + WS_CAND);
    uint4* Bmat = (uint4*)(ws + WS_BMAT);

    prep_kernel<<<dim3(864), dim3(256), 0, stream>>>(cb, Bhat, Bmat, out, cnt);
    argmin_kernel<<<dim3(NN / 256, MM), dim3(512), 0, stream>>>(
        z, Bmat, idxw, cnt, list, cand);
    cand_kernel<<<dim3(256), dim3(256), 0, stream>>>(
        z, cb, Bhat, cnt, list, cand, idxw, oflist);
    emul_kernel<<<dim3(256), dim3(256), 0, stream>>>(
        z, cb, Bhat, cnt, oflist, idxw);
    output_kernel<<<dim3(NN / 256, MM), dim3(256), 0, stream>>>(z, cb, idxw, out);
}